// Round 9
// baseline (377.829 us; speedup 1.0000x reference)
//
#include <hip/hip_runtime.h>
#include <hip/hip_bf16.h>

#define S_LEN 2048
#define D_MODEL 768
#define NH 12
#define DK 64
#define F_DIM 3072
#define BATCH 2
#define M_ROWS (BATCH * S_LEN)   // 4096

typedef __bf16 bf16x8 __attribute__((ext_vector_type(8)));
typedef float floatx4 __attribute__((ext_vector_type(4)));
typedef unsigned short u16;
typedef unsigned long long u64;

__device__ inline float bf2f(u16 u) {
    union { unsigned int i; float f; } x; x.i = ((unsigned int)u) << 16; return x.f;
}
__device__ inline u16 f2bf(float f) {
    union { float f; unsigned int i; } x; x.f = f;
    unsigned int r = x.i + 0x7fffu + ((x.i >> 16) & 1u);
    return (u16)(r >> 16);
}

// async global->LDS, 16B per lane; LDS dest is wave-uniform base + lane*16
__device__ __forceinline__ void ldsload16(const u16* g, u16* l) {
    __builtin_amdgcn_global_load_lds(
        (const __attribute__((address_space(1))) unsigned int*)g,
        (__attribute__((address_space(3))) unsigned int*)l, 16, 0, 0);
}

// ---------------- all weights f32 -> bf16, one launch -----------------------
// w1/w3 are interleaved into w13: 128-row super-blocks, rows 0-63 = w1 rows
// n*64..n*64+63, rows 64-127 = w3 rows n*64..n*64+63 (n = super-block index).
__global__ __launch_bounds__(256)
void cvt_all(const float4* __restrict__ wq, const float4* __restrict__ wk,
             const float4* __restrict__ wv, const float4* __restrict__ wo,
             const float4* __restrict__ w1, const float4* __restrict__ w2,
             const float4* __restrict__ w3,
             ushort4* wqb, ushort4* wkb, ushort4* wvb, ushort4* wob,
             ushort4* w13b, ushort4* w2b) {
    const int WS4 = (D_MODEL * D_MODEL) / 4;   // 147456
    const int WB4 = (F_DIM * D_MODEL) / 4;     // 589824
    const int RW4 = D_MODEL / 4;               // 192 float4 per row
    int i = blockIdx.x * 256 + threadIdx.x;
    const float4* src; ushort4* dst; int off, doff;
    if (i < 4 * WS4) {
        int s = i / WS4; off = i - s * WS4; doff = off;
        src = (s == 0) ? wq : (s == 1) ? wk : (s == 2) ? wv : wo;
        dst = (s == 0) ? wqb : (s == 1) ? wkb : (s == 2) ? wvb : wob;
    } else {
        int j = i - 4 * WS4; int s = j / WB4; off = j - s * WB4;
        if (s == 1) { src = w2; dst = w2b; doff = off; }
        else {
            src = (s == 0) ? w1 : w3;
            dst = w13b;
            int row = off / RW4, c4 = off - row * RW4;
            int rp = (row >> 6) * 128 + (row & 63) + ((s == 0) ? 0 : 64);
            doff = rp * RW4 + c4;
        }
    }
    float4 v = src[off];
    ushort4 o;
    o.x = f2bf(v.x); o.y = f2bf(v.y); o.z = f2bf(v.z); o.w = f2bf(v.w);
    dst[doff] = o;
}

// ---------------- mask -> bitmap (1 bit per key), wave ballot ---------------
__global__ __launch_bounds__(256)
void mask_bits(const int* __restrict__ m, u64* __restrict__ bits) {
    size_t gid = (size_t)blockIdx.x * 256 + threadIdx.x;
    u64 b = __ballot(m[gid] != 0);
    if ((threadIdx.x & 63) == 0) bits[gid >> 6] = b;
}

// ---------------- RMSNorm: f32 in, bf16 out, one block per row --------------
__global__ __launch_bounds__(256)
void rmsnorm_k(const float* __restrict__ x, const float* __restrict__ g, u16* __restrict__ out) {
    int row = blockIdx.x;
    const float* xr = x + (size_t)row * D_MODEL;
    u16* orow = out + (size_t)row * D_MODEL;
    int t = threadIdx.x;
    float v0 = xr[t];
    float v1 = xr[t + 256];
    float v2 = xr[t + 512];
    float ss = v0 * v0 + v1 * v1 + v2 * v2;
    #pragma unroll
    for (int off = 1; off < 64; off <<= 1) ss += __shfl_xor(ss, off);
    __shared__ float red[4];
    if ((t & 63) == 0) red[t >> 6] = ss;
    __syncthreads();
    float tot = red[0] + red[1] + red[2] + red[3];
    float scale = rsqrtf(tot * (1.0f / (float)D_MODEL) + 1e-5f);
    orow[t]       = f2bf(g[t]       * v0 * scale);
    orow[t + 256] = f2bf(g[t + 256] * v1 * scale);
    orow[t + 512] = f2bf(g[t + 512] * v2 * scale);
}

// ---------------- FFN1: 64m x 64out tile over interleaved w13 ---------------
// B-tile = 128 rows (64 w1 + 64 w3 for the same 64 outputs).
// C(bf16) = silu(A @ w1^T) * (A @ w3^T)
__global__ __launch_bounds__(256, 3)
void gemm_f1(const u16* __restrict__ A, const u16* __restrict__ W13,
             u16* __restrict__ Cout) {
    const int K = D_MODEL, N = F_DIM;
    __shared__ u16 As[2][64][32];
    __shared__ u16 Bs[2][128][32];

    int t = threadIdx.x;
    int w = t >> 6, lane = t & 63;
    int mBase = blockIdx.y * 64, nBase = blockIdx.x * 64;
    int lrow = lane & 15, quad = lane >> 4;
    int wm = (w >> 1) * 32, wn = (w & 1) * 32;

    int srow = lane >> 2, scol = (lane & 3) * 8;
    const u16* Ag = A   + (size_t)(mBase + w * 16 + srow) * K + scol;
    const u16* Bg = W13 + (size_t)(blockIdx.x * 128 + w * 32 + srow) * K + scol;

    auto stage = [&](int k0, int b) {
        ldsload16(Ag + k0, &As[b][w * 16][0]);
        ldsload16(Bg + k0, &Bs[b][w * 32][0]);
        ldsload16(Bg + (size_t)16 * K + k0, &Bs[b][w * 32 + 16][0]);
    };

    floatx4 zero = {0.f, 0.f, 0.f, 0.f};
    floatx4 acc[2][2], acc2[2][2];
    #pragma unroll
    for (int r = 0; r < 2; ++r)
        #pragma unroll
        for (int c = 0; c < 2; ++c) { acc[r][c] = zero; acc2[r][c] = zero; }

    stage(0, 0);
    int cur = 0;
    for (int k0 = 0; k0 < K; k0 += 32) {
        __syncthreads();
        if (k0 + 32 < K) stage(k0 + 32, cur ^ 1);

        bf16x8 af[2], b1f[2], b3f[2];
        #pragma unroll
        for (int r = 0; r < 2; ++r) af[r] = *(const bf16x8*)&As[cur][wm + r * 16 + lrow][quad * 8];
        #pragma unroll
        for (int c = 0; c < 2; ++c) {
            b1f[c] = *(const bf16x8*)&Bs[cur][wn + c * 16 + lrow][quad * 8];
            b3f[c] = *(const bf16x8*)&Bs[cur][64 + wn + c * 16 + lrow][quad * 8];
        }
        #pragma unroll
        for (int r = 0; r < 2; ++r)
            #pragma unroll
            for (int c = 0; c < 2; ++c) {
                acc[r][c]  = __builtin_amdgcn_mfma_f32_16x16x32_bf16(af[r], b1f[c], acc[r][c], 0, 0, 0);
                acc2[r][c] = __builtin_amdgcn_mfma_f32_16x16x32_bf16(af[r], b3f[c], acc2[r][c], 0, 0, 0);
            }
        cur ^= 1;
    }

    #pragma unroll
    for (int r = 0; r < 2; ++r) {
        #pragma unroll
        for (int c = 0; c < 2; ++c) {
            #pragma unroll
            for (int j = 0; j < 4; ++j) {
                int grow = mBase + wm + r * 16 + quad * 4 + j;
                int gcol = nBase + wn + c * 16 + lrow;
                float a = acc[r][c][j];
                Cout[(size_t)grow * N + gcol] = f2bf((a / (1.0f + __expf(-a))) * acc2[r][c][j]);
            }
        }
    }
}

// ---------------- 64x64-tile GEMM + residual (for N=768 GEMMs) --------------
__global__ __launch_bounds__(256, 3)
void gemm64(const u16* __restrict__ A, const u16* __restrict__ B1,
            const float* __restrict__ R, float* __restrict__ Cout, int N, int K) {
    __shared__ u16 As[2][64][32];
    __shared__ u16 Bs[2][64][32];

    int t = threadIdx.x;
    int w = t >> 6, lane = t & 63;
    int mBase = blockIdx.y * 64, nBase = blockIdx.x * 64;
    int lrow = lane & 15, quad = lane >> 4;
    int wm = (w >> 1) * 32, wn = (w & 1) * 32;

    int srow = lane >> 2, scol = (lane & 3) * 8;
    const u16* Ag = A  + (size_t)(mBase + w * 16 + srow) * K + scol;
    const u16* Bg = B1 + (size_t)(nBase + w * 16 + srow) * K + scol;

    auto stage = [&](int k0, int b) {
        ldsload16(Ag + k0, &As[b][w * 16][0]);
        ldsload16(Bg + k0, &Bs[b][w * 16][0]);
    };

    floatx4 zero = {0.f, 0.f, 0.f, 0.f};
    floatx4 acc[2][2];
    #pragma unroll
    for (int r = 0; r < 2; ++r)
        #pragma unroll
        for (int c = 0; c < 2; ++c) acc[r][c] = zero;

    stage(0, 0);
    int cur = 0;
    for (int k0 = 0; k0 < K; k0 += 32) {
        __syncthreads();
        if (k0 + 32 < K) stage(k0 + 32, cur ^ 1);

        bf16x8 af[2], bf[2];
        #pragma unroll
        for (int r = 0; r < 2; ++r) af[r] = *(const bf16x8*)&As[cur][wm + r * 16 + lrow][quad * 8];
        #pragma unroll
        for (int c = 0; c < 2; ++c) bf[c] = *(const bf16x8*)&Bs[cur][wn + c * 16 + lrow][quad * 8];
        #pragma unroll
        for (int r = 0; r < 2; ++r)
            #pragma unroll
            for (int c = 0; c < 2; ++c)
                acc[r][c] = __builtin_amdgcn_mfma_f32_16x16x32_bf16(af[r], bf[c], acc[r][c], 0, 0, 0);
        cur ^= 1;
    }

    #pragma unroll
    for (int r = 0; r < 2; ++r) {
        #pragma unroll
        for (int c = 0; c < 2; ++c) {
            #pragma unroll
            for (int j = 0; j < 4; ++j) {
                int grow = mBase + wm + r * 16 + quad * 4 + j;
                int gcol = nBase + wn + c * 16 + lrow;
                size_t idx = (size_t)grow * N + gcol;
                Cout[idx] = acc[r][c][j] + R[idx];
            }
        }
    }
}

// ---------------- fused QKV GEMM, 64x128 tile, V stored transposed ----------
// Q pre-scaled by 0.125*log2(e) so attention uses exp2 directly.
__global__ __launch_bounds__(256, 4)
void gemm_qkv(const u16* __restrict__ A, const u16* __restrict__ wq,
              const u16* __restrict__ wk, const u16* __restrict__ wv,
              u16* __restrict__ qb, u16* __restrict__ kb, u16* __restrict__ vt) {
    const int K = D_MODEL;
    __shared__ u16 As[2][64][32];
    __shared__ u16 Bs[2][128][32];

    int t = threadIdx.x;
    int w = t >> 6, lane = t & 63;
    int nb = blockIdx.x;
    int which = nb / 6;
    int mBase = blockIdx.y * 64, nBase = (nb % 6) * 128;
    const u16* B1 = (which == 0) ? wq : (which == 1) ? wk : wv;
    int lrow = lane & 15, quad = lane >> 4;
    int wm = (w >> 1) * 32, wn = (w & 1) * 64;

    int srow = lane >> 2, scol = (lane & 3) * 8;
    const u16* Ag = A  + (size_t)(mBase + w * 16 + srow) * K + scol;
    const u16* Bg = B1 + (size_t)(nBase + w * 32 + srow) * K + scol;

    auto stage = [&](int k0, int b) {
        ldsload16(Ag + k0, &As[b][w * 16][0]);
        ldsload16(Bg + k0, &Bs[b][w * 32][0]);
        ldsload16(Bg + (size_t)16 * K + k0, &Bs[b][w * 32 + 16][0]);
    };

    floatx4 zero = {0.f, 0.f, 0.f, 0.f};
    floatx4 acc[2][4];
    #pragma unroll
    for (int r = 0; r < 2; ++r)
        #pragma unroll
        for (int c = 0; c < 4; ++c) acc[r][c] = zero;

    stage(0, 0);
    int cur = 0;
    for (int k0 = 0; k0 < K; k0 += 32) {
        __syncthreads();
        if (k0 + 32 < K) stage(k0 + 32, cur ^ 1);
        bf16x8 af[2];
        #pragma unroll
        for (int r = 0; r < 2; ++r) af[r] = *(const bf16x8*)&As[cur][wm + r * 16 + lrow][quad * 8];
        #pragma unroll
        for (int c = 0; c < 4; ++c) {
            bf16x8 bfr = *(const bf16x8*)&Bs[cur][wn + c * 16 + lrow][quad * 8];
            #pragma unroll
            for (int r = 0; r < 2; ++r)
                acc[r][c] = __builtin_amdgcn_mfma_f32_16x16x32_bf16(af[r], bfr, acc[r][c], 0, 0, 0);
        }
        cur ^= 1;
    }

    u16* dst = (which == 0) ? qb : kb;
    const float qscale = 0.18033688011112042f;   // 0.125 * log2(e)
    #pragma unroll
    for (int r = 0; r < 2; ++r) {
        #pragma unroll
        for (int c = 0; c < 4; ++c) {
            #pragma unroll
            for (int j = 0; j < 4; ++j) {
                int grow = mBase + wm + r * 16 + quad * 4 + j;
                int gcol = nBase + wn + c * 16 + lrow;
                float val = acc[r][c][j];
                if (which == 2) {
                    int bb = grow >> 11, s = grow & 2047;
                    int hh = gcol >> 6, d = gcol & 63;
                    vt[((((size_t)bb * NH + hh) * DK + d) << 11) + s] = f2bf(val);
                } else {
                    if (which == 0) val *= qscale;
                    dst[(size_t)grow * D_MODEL + gcol] = f2bf(val);
                }
            }
        }
    }
}

// ---------------- MFMA flash attention (S^T formulation) --------------------
__global__ __launch_bounds__(256)
void attn_mfma(const u16* __restrict__ q, const u16* __restrict__ k,
               const u16* __restrict__ vt, const u64* __restrict__ mbits,
               u16* __restrict__ out) {
    __shared__ u16 Qs0[64][32], Qs1[64][32];
    __shared__ u16 Ks0[64][32], Ks1[64][32];
    __shared__ u16 Vs0[64][32], Vs1[64][32];
    __shared__ u16 PT[4][16][72];     // per-wave P^T relayout [q-local][key]

    int t = threadIdx.x;
    int lane = t & 63;
    int w = t >> 6;
    int lrow = lane & 15;
    int quad = lane >> 4;

    int st0 = blockIdx.x * 64;
    int bh = blockIdx.y;
    int h = bh % NH;
    int b = bh / NH;

    const u16* qbase = q + ((size_t)b * S_LEN + st0) * D_MODEL + h * DK;
    const u16* kbase = k + (size_t)b * S_LEN * D_MODEL + h * DK;
    const u16* vbase = vt + (size_t)bh * DK * S_LEN;
    const u64* bw = mbits + ((size_t)b * S_LEN + st0 + w * 16 + lrow) * (S_LEN / 64);

    int srow = lane >> 2;          // staging row within 16-row chunk
    int scol = (lane & 3) * 8;     // staging col (elems)

    // ---- stage Q tile (64x64) once ----
    const u16* qg = qbase + (size_t)(w * 16 + srow) * D_MODEL + scol;
    ldsload16(qg, &Qs0[w * 16][0]);
    ldsload16(qg + 32, &Qs1[w * 16][0]);
    __syncthreads();
    bf16x8 bq0 = *(const bf16x8*)&Qs0[w * 16 + lrow][quad * 8];
    bf16x8 bq1 = *(const bf16x8*)&Qs1[w * 16 + lrow][quad * 8];

    const u16* kg = kbase + (size_t)(w * 16 + srow) * D_MODEL + scol;
    const u16* vg = vbase + (size_t)(w * 16 + srow) * S_LEN + scol;

    // ones vector (bf16 1.0 x8) for MFMA row-sums
    bf16x8 ones;
    {
        union { u16 u; __bf16 b; } o; o.u = 0x3F80;
        #pragma unroll
        for (int j = 0; j < 8; ++j) ones[j] = o.b;
    }

    floatx4 zero = {0.f, 0.f, 0.f, 0.f};
    floatx4 Ot[4] = {zero, zero, zero, zero};
    floatx4 Osum = zero;              // row-sums of P (per-lane rows quad*4+j)

    for (int kt = 0; kt < S_LEN; kt += 64) {
        u64 mw = bw[kt >> 6];         // mask bits for this lane's q-row, 64 keys
        unsigned mlo = (unsigned)mw, mhi = (unsigned)(mw >> 32);
        __syncthreads();              // previous tile's LDS reads done
        ldsload16(kg + (size_t)kt * D_MODEL, &Ks0[w * 16][0]);
        ldsload16(kg + (size_t)kt * D_MODEL + 32, &Ks1[w * 16][0]);
        ldsload16(vg + kt, &Vs0[w * 16][0]);
        ldsload16(vg + kt + 32, &Vs1[w * 16][0]);
        __syncthreads();

        // --- S^T = K Q^T : 64 keys (rows) x 16 q (cols) per wave ---
        floatx4 st[4];
        #pragma unroll
        for (int nt = 0; nt < 4; ++nt) {
            bf16x8 ak0 = *(const bf16x8*)&Ks0[nt * 16 + lrow][quad * 8];
            bf16x8 ak1 = *(const bf16x8*)&Ks1[nt * 16 + lrow][quad * 8];
            st[nt] = __builtin_amdgcn_mfma_f32_16x16x32_bf16(ak0, bq0, zero, 0, 0, 0);
            st[nt] = __builtin_amdgcn_mfma_f32_16x16x32_bf16(ak1, bq1, st[nt], 0, 0, 0);
        }

        // --- P^T = maskbit * exp2(S^T), truncated to bf16, packed writes ---
        #pragma unroll
        for (int nt = 0; nt < 4; ++nt) {
            unsigned half = (nt & 2) ? mhi : mlo;
            unsigned tmp = half >> ((nt & 1) * 16 + quad * 4);
            unsigned eu[4];
            #pragma unroll
            for (int j = 0; j < 4; ++j) {
                float e = __builtin_amdgcn_exp2f(st[nt][j]);
                unsigned msk = (unsigned)((int)(tmp << (31 - j)) >> 31);
                eu[j] = __float_as_uint(e) & msk;
            }
            uint2 p;
            p.x = (eu[0] >> 16) | (eu[1] & 0xffff0000u);
            p.y = (eu[2] >> 16) | (eu[3] & 0xffff0000u);
            *(uint2*)&PT[w][lrow][nt * 16 + quad * 4] = p;
        }

        // --- O += P V ; row-sums += P * ones (on the MFMA pipe) ---
        bf16x8 ap0 = *(const bf16x8*)&PT[w][lrow][quad * 8];
        bf16x8 ap1 = *(const bf16x8*)&PT[w][lrow][32 + quad * 8];
        Osum = __builtin_amdgcn_mfma_f32_16x16x32_bf16(ap0, ones, Osum, 0, 0, 0);
        Osum = __builtin_amdgcn_mfma_f32_16x16x32_bf16(ap1, ones, Osum, 0, 0, 0);
        #pragma unroll
        for (int dt = 0; dt < 4; ++dt) {
            bf16x8 bv0 = *(const bf16x8*)&Vs0[dt * 16 + lrow][quad * 8];
            bf16x8 bv1 = *(const bf16x8*)&Vs1[dt * 16 + lrow][quad * 8];
            Ot[dt] = __builtin_amdgcn_mfma_f32_16x16x32_bf16(ap0, bv0, Ot[dt], 0, 0, 0);
            Ot[dt] = __builtin_amdgcn_mfma_f32_16x16x32_bf16(ap1, bv1, Ot[dt], 0, 0, 0);
        }
    }

    // --- Osum[j] is the row-sum for q-row quad*4+j (cols identical) ---
    float invj[4];
    #pragma unroll
    for (int j = 0; j < 4; ++j) invj[j] = 1.0f / Osum[j];

    u16* obase = out + ((size_t)b * S_LEN + st0 + w * 16) * D_MODEL + h * DK;
    #pragma unroll
    for (int dt = 0; dt < 4; ++dt)
        #pragma unroll
        for (int j = 0; j < 4; ++j)
            obase[(size_t)(quad * 4 + j) * D_MODEL + dt * 16 + lrow] = f2bf(Ot[dt][j] * invj[j]);
}

// ---------------- host launch ----------------
extern "C" void kernel_launch(void* const* d_in, const int* in_sizes, int n_in,
                              void* d_out, int out_size, void* d_ws, size_t ws_size,
                              hipStream_t stream) {
    const float* x      = (const float*)d_in[0];
    const int*   mask   = (const int*)d_in[1];
    const float* wq     = (const float*)d_in[2];
    const float* wk     = (const float*)d_in[3];
    const float* wv     = (const float*)d_in[4];
    const float* wo     = (const float*)d_in[5];
    const float* w1     = (const float*)d_in[6];
    const float* w2     = (const float*)d_in[7];
    const float* w3     = (const float*)d_in[8];
    const float* g_attn = (const float*)d_in[9];
    const float* g_ffn  = (const float*)d_in[10];
    float* out = (float*)d_out;

    const size_t WSMALL = (size_t)D_MODEL * D_MODEL;
    const size_t WBIG   = (size_t)F_DIM * D_MODEL;
    const size_t MD     = (size_t)M_ROWS * D_MODEL;

    char* ws = (char*)d_ws;
    u16* wqb  = (u16*)ws;            ws += WSMALL * 2;
    u16* wkb  = (u16*)ws;            ws += WSMALL * 2;
    u16* wvb  = (u16*)ws;            ws += WSMALL * 2;
    u16* wob  = (u16*)ws;            ws += WSMALL * 2;
    u16* w13b = (u16*)ws;            ws += WBIG * 2 * 2;   // interleaved w1|w3
    u16* w2b  = (u16*)ws;            ws += WBIG * 2;
    u16* xn  = (u16*)ws;             ws += MD * 2;       // also hn (reuse)
    u16* qb  = (u16*)ws;             ws += MD * 2;       // qb..ao contiguous = ub [M,F]
    u16* kb  = (u16*)ws;             ws += MD * 2;
    u16* vb  = (u16*)ws;             ws += MD * 2;       // V^T [B][NH][DK][S]
    u16* ao  = (u16*)ws;             ws += MD * 2;
    float* hb = (float*)ws;          ws += MD * 4;
    u64* mb  = (u64*)ws;             ws += (size_t)BATCH * S_LEN * (S_LEN / 64) * 8;
    u16* hn = xn;
    u16* ub = qb;   // [M, F] bf16, reuses qb..ao (4*MD == M*F)
    (void)ws_size; (void)n_in; (void)in_sizes; (void)out_size;

    dim3 blk(256);

    cvt_all<<<9216, blk, 0, stream>>>((const float4*)wq, (const float4*)wk, (const float4*)wv,
                                      (const float4*)wo, (const float4*)w1, (const float4*)w2,
                                      (const float4*)w3,
                                      (ushort4*)wqb, (ushort4*)wkb, (ushort4*)wvb, (ushort4*)wob,
                                      (ushort4*)w13b, (ushort4*)w2b);
    mask_bits<<<(BATCH * S_LEN * S_LEN) / 256, blk, 0, stream>>>(mask, mb);

    rmsnorm_k<<<M_ROWS, blk, 0, stream>>>(x, g_attn, xn);
    gemm_qkv<<<dim3(18, M_ROWS / 64), blk, 0, stream>>>(xn, wqb, wkb, wvb, qb, kb, vb);
    attn_mfma<<<dim3(S_LEN / 64, BATCH * NH), blk, 0, stream>>>(qb, kb, vb, mb, ao);
    gemm64<<<dim3(D_MODEL / 64, M_ROWS / 64), blk, 0, stream>>>(ao, wob, x, hb, D_MODEL, D_MODEL);
    rmsnorm_k<<<M_ROWS, blk, 0, stream>>>((const float*)hb, g_ffn, hn);
    gemm_f1<<<dim3(F_DIM / 64, M_ROWS / 64), blk, 0, stream>>>(hn, w13b, ub);
    gemm64<<<dim3(D_MODEL / 64, M_ROWS / 64), blk, 0, stream>>>(ub, w2b, hb, out, D_MODEL, F_DIM);
}

// Round 10
// 360.121 us; speedup vs baseline: 1.0492x; 1.0492x over previous
//
#include <hip/hip_runtime.h>
#include <hip/hip_bf16.h>

#define S_LEN 2048
#define D_MODEL 768
#define NH 12
#define DK 64
#define F_DIM 3072
#define BATCH 2
#define M_ROWS (BATCH * S_LEN)   // 4096

typedef __bf16 bf16x8 __attribute__((ext_vector_type(8)));
typedef float floatx4 __attribute__((ext_vector_type(4)));
typedef unsigned short u16;
typedef unsigned long long u64;

__device__ inline float bf2f(u16 u) {
    union { unsigned int i; float f; } x; x.i = ((unsigned int)u) << 16; return x.f;
}
__device__ inline u16 f2bf(float f) {
    union { float f; unsigned int i; } x; x.f = f;
    unsigned int r = x.i + 0x7fffu + ((x.i >> 16) & 1u);
    return (u16)(r >> 16);
}
__device__ __forceinline__ bf16x8 as_bf16x8(uint4 v) {
    union { uint4 u; bf16x8 b; } c; c.u = v; return c.b;
}

// async global->LDS, 16B per lane; LDS dest is wave-uniform base + lane*16
__device__ __forceinline__ void ldsload16(const u16* g, u16* l) {
    __builtin_amdgcn_global_load_lds(
        (const __attribute__((address_space(1))) unsigned int*)g,
        (__attribute__((address_space(3))) unsigned int*)l, 16, 0, 0);
}

// ---------------- all weights f32 -> bf16, one launch -----------------------
// w1/w3 go to w13f in MFMA-fragment order: frag id f = ((n_tile*24 + k_tile)*2
// + which), each frag 512 u16 (lane l holds W[n_tile*16 + (l&15)][k_tile*32 +
// (l>>4)*8 + j], j=0..7 at elem f*512 + l*8 + j). B-frags then load from
// global as one coalesced dwordx4 per lane — no LDS, no bank conflicts.
__global__ __launch_bounds__(256)
void cvt_all(const float4* __restrict__ wq, const float4* __restrict__ wk,
             const float4* __restrict__ wv, const float4* __restrict__ wo,
             const float4* __restrict__ w1, const float4* __restrict__ w2,
             const float4* __restrict__ w3,
             ushort4* wqb, ushort4* wkb, ushort4* wvb, ushort4* wob,
             ushort4* w13f, ushort4* w2b) {
    const int WS4 = (D_MODEL * D_MODEL) / 4;   // 147456
    const int WB4 = (F_DIM * D_MODEL) / 4;     // 589824
    const int RW4 = D_MODEL / 4;               // 192 float4 per row
    int i = blockIdx.x * 256 + threadIdx.x;
    const float4* src; ushort4* dst; int off, doff;
    if (i < 4 * WS4) {
        int s = i / WS4; off = i - s * WS4; doff = off;
        src = (s == 0) ? wq : (s == 1) ? wk : (s == 2) ? wv : wo;
        dst = (s == 0) ? wqb : (s == 1) ? wkb : (s == 2) ? wvb : wob;
    } else {
        int j = i - 4 * WS4; int s = j / WB4; off = j - s * WB4;
        if (s == 1) { src = w2; dst = w2b; doff = off; }
        else {
            src = (s == 0) ? w1 : w3;
            dst = w13f;
            int which = (s == 0) ? 0 : 1;
            int row = off / RW4, c4 = off - row * RW4;
            int k = c4 * 4;
            int n_tile = row >> 4, nl = row & 15;
            int k_tile = k >> 5, quad = (k >> 3) & 3, jj = k & 7;
            int lane = quad * 16 + nl;
            int f = (n_tile * 24 + k_tile) * 2 + which;
            doff = (f * 512 + lane * 8 + jj) >> 2;
        }
    }
    float4 v = src[off];
    ushort4 o;
    o.x = f2bf(v.x); o.y = f2bf(v.y); o.z = f2bf(v.z); o.w = f2bf(v.w);
    dst[doff] = o;
}

// ---------------- mask -> bitmap (1 bit per key), wave ballot ---------------
__global__ __launch_bounds__(256)
void mask_bits(const int* __restrict__ m, u64* __restrict__ bits) {
    size_t gid = (size_t)blockIdx.x * 256 + threadIdx.x;
    u64 b = __ballot(m[gid] != 0);
    if ((threadIdx.x & 63) == 0) bits[gid >> 6] = b;
}

// ---------------- RMSNorm: f32 in, bf16 out, one block per row --------------
__global__ __launch_bounds__(256)
void rmsnorm_k(const float* __restrict__ x, const float* __restrict__ g, u16* __restrict__ out) {
    int row = blockIdx.x;
    const float* xr = x + (size_t)row * D_MODEL;
    u16* orow = out + (size_t)row * D_MODEL;
    int t = threadIdx.x;
    float v0 = xr[t];
    float v1 = xr[t + 256];
    float v2 = xr[t + 512];
    float ss = v0 * v0 + v1 * v1 + v2 * v2;
    #pragma unroll
    for (int off = 1; off < 64; off <<= 1) ss += __shfl_xor(ss, off);
    __shared__ float red[4];
    if ((t & 63) == 0) red[t >> 6] = ss;
    __syncthreads();
    float tot = red[0] + red[1] + red[2] + red[3];
    float scale = rsqrtf(tot * (1.0f / (float)D_MODEL) + 1e-5f);
    orow[t]       = f2bf(g[t]       * v0 * scale);
    orow[t + 256] = f2bf(g[t + 256] * v1 * scale);
    orow[t + 512] = f2bf(g[t + 512] * v2 * scale);
}

// ---------------- FFN1: direct-global B-frags, A LDS-staged -----------------
// Block = 64m x 128out (4 waves, each 64m x 32out-pair). B-frags stream from
// global (L2) in fragment layout; XCD-swizzled grid keeps each XCD's weight
// slice (1.15 MB) L2-resident. C(bf16) = silu(A@w1^T) * (A@w3^T).
__global__ __launch_bounds__(256, 3)
void gemm_f1(const u16* __restrict__ A, const u16* __restrict__ W13f,
             u16* __restrict__ Cout) {
    const int K = D_MODEL, N = F_DIM;
    __shared__ u16 As[2][64][32];

    int t = threadIdx.x;
    int w = t >> 6, lane = t & 63;
    int lrow = lane & 15, quad = lane >> 4;

    int lid = blockIdx.y * 24 + blockIdx.x;
    int xcd = lid & 7, s = lid >> 3;          // 192 blocks per xcd
    int nb = xcd * 3 + (s % 3);               // 0..23
    int mb = s / 3;                           // 0..63
    int mBase = mb * 64;
    int ntile0 = nb * 8 + w * 2;              // wave's first n-tile

    int srow = lane >> 2, scol = (lane & 3) * 8;
    const u16* Ag = A + (size_t)(mBase + w * 16 + srow) * K + scol;
    const uint4* Bf = (const uint4*)W13f;

    auto stageA = [&](int k0, int b) {
        ldsload16(Ag + k0, &As[b][w * 16][0]);
    };

    floatx4 zero = {0.f, 0.f, 0.f, 0.f};
    floatx4 acc[4][2], acc2[4][2];
    #pragma unroll
    for (int r = 0; r < 4; ++r)
        #pragma unroll
        for (int c = 0; c < 2; ++c) { acc[r][c] = zero; acc2[r][c] = zero; }

    stageA(0, 0);
    int cur = 0;
    for (int kt = 0; kt < 24; ++kt) {
        // B-frags for this K-chunk: independent of LDS, issue early
        uint4 b1v[2], b3v[2];
        #pragma unroll
        for (int c = 0; c < 2; ++c) {
            int f = ((ntile0 + c) * 24 + kt) * 2;
            b1v[c] = Bf[(size_t)f * 64 + lane];
            b3v[c] = Bf[(size_t)(f + 1) * 64 + lane];
        }
        __syncthreads();                       // stageA(kt) landed
        if (kt + 1 < 24) stageA((kt + 1) * 32, cur ^ 1);

        bf16x8 af[4];
        #pragma unroll
        for (int r = 0; r < 4; ++r) af[r] = *(const bf16x8*)&As[cur][r * 16 + lrow][quad * 8];
        #pragma unroll
        for (int c = 0; c < 2; ++c) {
            bf16x8 b1f = as_bf16x8(b1v[c]);
            bf16x8 b3f = as_bf16x8(b3v[c]);
            #pragma unroll
            for (int r = 0; r < 4; ++r) {
                acc[r][c]  = __builtin_amdgcn_mfma_f32_16x16x32_bf16(af[r], b1f, acc[r][c], 0, 0, 0);
                acc2[r][c] = __builtin_amdgcn_mfma_f32_16x16x32_bf16(af[r], b3f, acc2[r][c], 0, 0, 0);
            }
        }
        cur ^= 1;
    }

    #pragma unroll
    for (int r = 0; r < 4; ++r) {
        #pragma unroll
        for (int c = 0; c < 2; ++c) {
            #pragma unroll
            for (int j = 0; j < 4; ++j) {
                int grow = mBase + r * 16 + quad * 4 + j;
                int gcol = nb * 128 + w * 32 + c * 16 + lrow;
                float a = acc[r][c][j];
                Cout[(size_t)grow * N + gcol] = f2bf((a / (1.0f + __expf(-a))) * acc2[r][c][j]);
            }
        }
    }
}

// ---------------- 64x64-tile GEMM + residual (for N=768 GEMMs) --------------
__global__ __launch_bounds__(256, 3)
void gemm64(const u16* __restrict__ A, const u16* __restrict__ B1,
            const float* __restrict__ R, float* __restrict__ Cout, int N, int K) {
    __shared__ u16 As[2][64][32];
    __shared__ u16 Bs[2][64][32];

    int t = threadIdx.x;
    int w = t >> 6, lane = t & 63;
    int mBase = blockIdx.y * 64, nBase = blockIdx.x * 64;
    int lrow = lane & 15, quad = lane >> 4;
    int wm = (w >> 1) * 32, wn = (w & 1) * 32;

    int srow = lane >> 2, scol = (lane & 3) * 8;
    const u16* Ag = A  + (size_t)(mBase + w * 16 + srow) * K + scol;
    const u16* Bg = B1 + (size_t)(nBase + w * 16 + srow) * K + scol;

    auto stage = [&](int k0, int b) {
        ldsload16(Ag + k0, &As[b][w * 16][0]);
        ldsload16(Bg + k0, &Bs[b][w * 16][0]);
    };

    floatx4 zero = {0.f, 0.f, 0.f, 0.f};
    floatx4 acc[2][2];
    #pragma unroll
    for (int r = 0; r < 2; ++r)
        #pragma unroll
        for (int c = 0; c < 2; ++c) acc[r][c] = zero;

    stage(0, 0);
    int cur = 0;
    for (int k0 = 0; k0 < K; k0 += 32) {
        __syncthreads();
        if (k0 + 32 < K) stage(k0 + 32, cur ^ 1);

        bf16x8 af[2], bf[2];
        #pragma unroll
        for (int r = 0; r < 2; ++r) af[r] = *(const bf16x8*)&As[cur][wm + r * 16 + lrow][quad * 8];
        #pragma unroll
        for (int c = 0; c < 2; ++c) bf[c] = *(const bf16x8*)&Bs[cur][wn + c * 16 + lrow][quad * 8];
        #pragma unroll
        for (int r = 0; r < 2; ++r)
            #pragma unroll
            for (int c = 0; c < 2; ++c)
                acc[r][c] = __builtin_amdgcn_mfma_f32_16x16x32_bf16(af[r], bf[c], acc[r][c], 0, 0, 0);
        cur ^= 1;
    }

    #pragma unroll
    for (int r = 0; r < 2; ++r) {
        #pragma unroll
        for (int c = 0; c < 2; ++c) {
            #pragma unroll
            for (int j = 0; j < 4; ++j) {
                int grow = mBase + wm + r * 16 + quad * 4 + j;
                int gcol = nBase + wn + c * 16 + lrow;
                size_t idx = (size_t)grow * N + gcol;
                Cout[idx] = acc[r][c][j] + R[idx];
            }
        }
    }
}

// ---------------- fused QKV GEMM, 64x128 tile, V stored transposed ----------
// Q pre-scaled by 0.125*log2(e) so attention uses exp2 directly.
__global__ __launch_bounds__(256, 4)
void gemm_qkv(const u16* __restrict__ A, const u16* __restrict__ wq,
              const u16* __restrict__ wk, const u16* __restrict__ wv,
              u16* __restrict__ qb, u16* __restrict__ kb, u16* __restrict__ vt) {
    const int K = D_MODEL;
    __shared__ u16 As[2][64][32];
    __shared__ u16 Bs[2][128][32];

    int t = threadIdx.x;
    int w = t >> 6, lane = t & 63;
    int nb = blockIdx.x;
    int which = nb / 6;
    int mBase = blockIdx.y * 64, nBase = (nb % 6) * 128;
    const u16* B1 = (which == 0) ? wq : (which == 1) ? wk : wv;
    int lrow = lane & 15, quad = lane >> 4;
    int wm = (w >> 1) * 32, wn = (w & 1) * 64;

    int srow = lane >> 2, scol = (lane & 3) * 8;
    const u16* Ag = A  + (size_t)(mBase + w * 16 + srow) * K + scol;
    const u16* Bg = B1 + (size_t)(nBase + w * 32 + srow) * K + scol;

    auto stage = [&](int k0, int b) {
        ldsload16(Ag + k0, &As[b][w * 16][0]);
        ldsload16(Bg + k0, &Bs[b][w * 32][0]);
        ldsload16(Bg + (size_t)16 * K + k0, &Bs[b][w * 32 + 16][0]);
    };

    floatx4 zero = {0.f, 0.f, 0.f, 0.f};
    floatx4 acc[2][4];
    #pragma unroll
    for (int r = 0; r < 2; ++r)
        #pragma unroll
        for (int c = 0; c < 4; ++c) acc[r][c] = zero;

    stage(0, 0);
    int cur = 0;
    for (int k0 = 0; k0 < K; k0 += 32) {
        __syncthreads();
        if (k0 + 32 < K) stage(k0 + 32, cur ^ 1);
        bf16x8 af[2];
        #pragma unroll
        for (int r = 0; r < 2; ++r) af[r] = *(const bf16x8*)&As[cur][wm + r * 16 + lrow][quad * 8];
        #pragma unroll
        for (int c = 0; c < 4; ++c) {
            bf16x8 bfr = *(const bf16x8*)&Bs[cur][wn + c * 16 + lrow][quad * 8];
            #pragma unroll
            for (int r = 0; r < 2; ++r)
                acc[r][c] = __builtin_amdgcn_mfma_f32_16x16x32_bf16(af[r], bfr, acc[r][c], 0, 0, 0);
        }
        cur ^= 1;
    }

    u16* dst = (which == 0) ? qb : kb;
    const float qscale = 0.18033688011112042f;   // 0.125 * log2(e)
    #pragma unroll
    for (int r = 0; r < 2; ++r) {
        #pragma unroll
        for (int c = 0; c < 4; ++c) {
            #pragma unroll
            for (int j = 0; j < 4; ++j) {
                int grow = mBase + wm + r * 16 + quad * 4 + j;
                int gcol = nBase + wn + c * 16 + lrow;
                float val = acc[r][c][j];
                if (which == 2) {
                    int bb = grow >> 11, s = grow & 2047;
                    int hh = gcol >> 6, d = gcol & 63;
                    vt[((((size_t)bb * NH + hh) * DK + d) << 11) + s] = f2bf(val);
                } else {
                    if (which == 0) val *= qscale;
                    dst[(size_t)grow * D_MODEL + gcol] = f2bf(val);
                }
            }
        }
    }
}

// ---------------- MFMA flash attention (S^T formulation) --------------------
__global__ __launch_bounds__(256)
void attn_mfma(const u16* __restrict__ q, const u16* __restrict__ k,
               const u16* __restrict__ vt, const u64* __restrict__ mbits,
               u16* __restrict__ out) {
    __shared__ u16 Qs0[64][32], Qs1[64][32];
    __shared__ u16 Ks0[64][32], Ks1[64][32];
    __shared__ u16 Vs0[64][32], Vs1[64][32];
    __shared__ u16 PT[4][16][72];     // per-wave P^T relayout [q-local][key]

    int t = threadIdx.x;
    int lane = t & 63;
    int w = t >> 6;
    int lrow = lane & 15;
    int quad = lane >> 4;

    int st0 = blockIdx.x * 64;
    int bh = blockIdx.y;
    int h = bh % NH;
    int b = bh / NH;

    const u16* qbase = q + ((size_t)b * S_LEN + st0) * D_MODEL + h * DK;
    const u16* kbase = k + (size_t)b * S_LEN * D_MODEL + h * DK;
    const u16* vbase = vt + (size_t)bh * DK * S_LEN;
    const u64* bw = mbits + ((size_t)b * S_LEN + st0 + w * 16 + lrow) * (S_LEN / 64);

    int srow = lane >> 2;          // staging row within 16-row chunk
    int scol = (lane & 3) * 8;     // staging col (elems)

    // ---- stage Q tile (64x64) once ----
    const u16* qg = qbase + (size_t)(w * 16 + srow) * D_MODEL + scol;
    ldsload16(qg, &Qs0[w * 16][0]);
    ldsload16(qg + 32, &Qs1[w * 16][0]);
    __syncthreads();
    bf16x8 bq0 = *(const bf16x8*)&Qs0[w * 16 + lrow][quad * 8];
    bf16x8 bq1 = *(const bf16x8*)&Qs1[w * 16 + lrow][quad * 8];

    const u16* kg = kbase + (size_t)(w * 16 + srow) * D_MODEL + scol;
    const u16* vg = vbase + (size_t)(w * 16 + srow) * S_LEN + scol;

    // ones vector (bf16 1.0 x8) for MFMA row-sums
    bf16x8 ones;
    {
        union { u16 u; __bf16 b; } o; o.u = 0x3F80;
        #pragma unroll
        for (int j = 0; j < 8; ++j) ones[j] = o.b;
    }

    floatx4 zero = {0.f, 0.f, 0.f, 0.f};
    floatx4 Ot[4] = {zero, zero, zero, zero};
    floatx4 Osum = zero;              // row-sums of P (per-lane rows quad*4+j)

    for (int kt = 0; kt < S_LEN; kt += 64) {
        u64 mw = bw[kt >> 6];         // mask bits for this lane's q-row, 64 keys
        unsigned mlo = (unsigned)mw, mhi = (unsigned)(mw >> 32);
        __syncthreads();              // previous tile's LDS reads done
        ldsload16(kg + (size_t)kt * D_MODEL, &Ks0[w * 16][0]);
        ldsload16(kg + (size_t)kt * D_MODEL + 32, &Ks1[w * 16][0]);
        ldsload16(vg + kt, &Vs0[w * 16][0]);
        ldsload16(vg + kt + 32, &Vs1[w * 16][0]);
        __syncthreads();

        // --- S^T = K Q^T : 64 keys (rows) x 16 q (cols) per wave ---
        floatx4 st[4];
        #pragma unroll
        for (int nt = 0; nt < 4; ++nt) {
            bf16x8 ak0 = *(const bf16x8*)&Ks0[nt * 16 + lrow][quad * 8];
            bf16x8 ak1 = *(const bf16x8*)&Ks1[nt * 16 + lrow][quad * 8];
            st[nt] = __builtin_amdgcn_mfma_f32_16x16x32_bf16(ak0, bq0, zero, 0, 0, 0);
            st[nt] = __builtin_amdgcn_mfma_f32_16x16x32_bf16(ak1, bq1, st[nt], 0, 0, 0);
        }

        // --- P^T = maskbit * exp2(S^T), truncated to bf16, packed writes ---
        #pragma unroll
        for (int nt = 0; nt < 4; ++nt) {
            unsigned half = (nt & 2) ? mhi : mlo;
            unsigned tmp = half >> ((nt & 1) * 16 + quad * 4);
            unsigned eu[4];
            #pragma unroll
            for (int j = 0; j < 4; ++j) {
                float e = __builtin_amdgcn_exp2f(st[nt][j]);
                unsigned msk = (unsigned)((int)(tmp << (31 - j)) >> 31);
                eu[j] = __float_as_uint(e) & msk;
            }
            uint2 p;
            p.x = (eu[0] >> 16) | (eu[1] & 0xffff0000u);
            p.y = (eu[2] >> 16) | (eu[3] & 0xffff0000u);
            *(uint2*)&PT[w][lrow][nt * 16 + quad * 4] = p;
        }

        // --- O += P V ; row-sums += P * ones (on the MFMA pipe) ---
        bf16x8 ap0 = *(const bf16x8*)&PT[w][lrow][quad * 8];
        bf16x8 ap1 = *(const bf16x8*)&PT[w][lrow][32 + quad * 8];
        Osum = __builtin_amdgcn_mfma_f32_16x16x32_bf16(ap0, ones, Osum, 0, 0, 0);
        Osum = __builtin_amdgcn_mfma_f32_16x16x32_bf16(ap1, ones, Osum, 0, 0, 0);
        #pragma unroll
        for (int dt = 0; dt < 4; ++dt) {
            bf16x8 bv0 = *(const bf16x8*)&Vs0[dt * 16 + lrow][quad * 8];
            bf16x8 bv1 = *(const bf16x8*)&Vs1[dt * 16 + lrow][quad * 8];
            Ot[dt] = __builtin_amdgcn_mfma_f32_16x16x32_bf16(ap0, bv0, Ot[dt], 0, 0, 0);
            Ot[dt] = __builtin_amdgcn_mfma_f32_16x16x32_bf16(ap1, bv1, Ot[dt], 0, 0, 0);
        }
    }

    // --- Osum[j] is the row-sum for q-row quad*4+j (cols identical) ---
    float invj[4];
    #pragma unroll
    for (int j = 0; j < 4; ++j) invj[j] = 1.0f / Osum[j];

    u16* obase = out + ((size_t)b * S_LEN + st0 + w * 16) * D_MODEL + h * DK;
    #pragma unroll
    for (int dt = 0; dt < 4; ++dt)
        #pragma unroll
        for (int j = 0; j < 4; ++j)
            obase[(size_t)(quad * 4 + j) * D_MODEL + dt * 16 + lrow] = f2bf(Ot[dt][j] * invj[j]);
}

// ---------------- host launch ----------------
extern "C" void kernel_launch(void* const* d_in, const int* in_sizes, int n_in,
                              void* d_out, int out_size, void* d_ws, size_t ws_size,
                              hipStream_t stream) {
    const float* x      = (const float*)d_in[0];
    const int*   mask   = (const int*)d_in[1];
    const float* wq     = (const float*)d_in[2];
    const float* wk     = (const float*)d_in[3];
    const float* wv     = (const float*)d_in[4];
    const float* wo     = (const float*)d_in[5];
    const float* w1     = (const float*)d_in[6];
    const float* w2     = (const float*)d_in[7];
    const float* w3     = (const float*)d_in[8];
    const float* g_attn = (const float*)d_in[9];
    const float* g_ffn  = (const float*)d_in[10];
    float* out = (float*)d_out;

    const size_t WSMALL = (size_t)D_MODEL * D_MODEL;
    const size_t WBIG   = (size_t)F_DIM * D_MODEL;
    const size_t MD     = (size_t)M_ROWS * D_MODEL;

    char* ws = (char*)d_ws;
    u16* wqb  = (u16*)ws;            ws += WSMALL * 2;
    u16* wkb  = (u16*)ws;            ws += WSMALL * 2;
    u16* wvb  = (u16*)ws;            ws += WSMALL * 2;
    u16* wob  = (u16*)ws;            ws += WSMALL * 2;
    u16* w13f = (u16*)ws;            ws += WBIG * 2 * 2;   // frag-ordered w1|w3
    u16* w2b  = (u16*)ws;            ws += WBIG * 2;
    u16* xn  = (u16*)ws;             ws += MD * 2;       // also hn (reuse)
    u16* qb  = (u16*)ws;             ws += MD * 2;       // qb..ao contiguous = ub [M,F]
    u16* kb  = (u16*)ws;             ws += MD * 2;
    u16* vb  = (u16*)ws;             ws += MD * 2;       // V^T [B][NH][DK][S]
    u16* ao  = (u16*)ws;             ws += MD * 2;
    float* hb = (float*)ws;          ws += MD * 4;
    u64* mb  = (u64*)ws;             ws += (size_t)BATCH * S_LEN * (S_LEN / 64) * 8;
    u16* hn = xn;
    u16* ub = qb;   // [M, F] bf16, reuses qb..ao (4*MD == M*F)
    (void)ws_size; (void)n_in; (void)in_sizes; (void)out_size;

    dim3 blk(256);

    cvt_all<<<9216, blk, 0, stream>>>((const float4*)wq, (const float4*)wk, (const float4*)wv,
                                      (const float4*)wo, (const float4*)w1, (const float4*)w2,
                                      (const float4*)w3,
                                      (ushort4*)wqb, (ushort4*)wkb, (ushort4*)wvb, (ushort4*)wob,
                                      (ushort4*)w13f, (ushort4*)w2b);
    mask_bits<<<(BATCH * S_LEN * S_LEN) / 256, blk, 0, stream>>>(mask, mb);

    rmsnorm_k<<<M_ROWS, blk, 0, stream>>>(x, g_attn, xn);
    gemm_qkv<<<dim3(18, M_ROWS / 64), blk, 0, stream>>>(xn, wqb, wkb, wvb, qb, kb, vb);
    attn_mfma<<<dim3(S_LEN / 64, BATCH * NH), blk, 0, stream>>>(qb, kb, vb, mb, ao);
    gemm64<<<dim3(D_MODEL / 64, M_ROWS / 64), blk, 0, stream>>>(ao, wob, x, hb, D_MODEL, D_MODEL);
    rmsnorm_k<<<M_ROWS, blk, 0, stream>>>((const float*)hb, g_ffn, hn);
    gemm_f1<<<dim3(24, M_ROWS / 64), blk, 0, stream>>>(hn, w13f, ub);
    gemm64<<<dim3(D_MODEL / 64, M_ROWS / 64), blk, 0, stream>>>(ub, w2b, hb, out, D_MODEL, F_DIM);
}